// Round 11
// baseline (104.963 us; speedup 1.0000x reference)
//
#include <hip/hip_runtime.h>

#define N 4096
#define D 256
#define MARGIN 0.3f
#define BIG 10000.0f

typedef _Float16 f16x8 __attribute__((ext_vector_type(8)));
typedef _Float16 f16x4 __attribute__((ext_vector_type(4)));
typedef float floatx16 __attribute__((ext_vector_type(16)));

__device__ inline void atomicMaxFloatPos(float* a, float v) {
    atomicMax((int*)a, __float_as_int(v));   // valid: all values >= 0
}
__device__ inline void atomicMinFloatPos(float* a, float v) {
    atomicMin((int*)a, __float_as_int(v));
}

// async 16B global -> LDS (wave-uniform LDS base + lane*16)
__device__ inline void gl_lds16(const void* g, void* l) {
    __builtin_amdgcn_global_load_lds(
        (const __attribute__((address_space(1))) unsigned int*)g,
        (__attribute__((address_space(3))) unsigned int*)l, 16, 0, 0);
}

// Wave per row: convert x -> fp16 Xf (RNE, row-major), sq from the CONVERTED
// values (so the Gram diagonal cancels exactly), init ap/ang/anl; block 0
// zeroes the two scalar outputs (finish accumulates into them via atomicAdd).
__global__ __launch_bounds__(256) void prep_kernel(const float* __restrict__ x,
                                                   float* __restrict__ sq,
                                                   _Float16* __restrict__ Xf,
                                                   float* ap, float* ang, float* anl,
                                                   float* __restrict__ out) {
    const int wave = threadIdx.x >> 6, lane = threadIdx.x & 63;
    const int row = blockIdx.x * 4 + wave;
    const float4 v = *(const float4*)(x + (size_t)row * D + lane * 4);
    f16x4 h;
    h[0] = (_Float16)v.x; h[1] = (_Float16)v.y;
    h[2] = (_Float16)v.z; h[3] = (_Float16)v.w;
    *(f16x4*)(Xf + (size_t)row * D + lane * 4) = h;
    const float c0 = (float)h[0], c1 = (float)h[1], c2 = (float)h[2], c3 = (float)h[3];
    float s = c0 * c0 + c1 * c1 + c2 * c2 + c3 * c3;
    #pragma unroll
    for (int off = 32; off; off >>= 1) s += __shfl_down(s, off);
    if (lane == 0) sq[row] = s;
    if (threadIdx.x < 4) {
        const int i = blockIdx.x * 4 + threadIdx.x;
        ap[i] = 0.0f; ang[i] = BIG; anl[i] = BIG;
    }
    if (blockIdx.x == 0 && threadIdx.x == 0) {
        out[0] = 0.0f;                       // loss accumulator
        out[1 + (size_t)N * N] = 0.0f;       // cnt accumulator
    }
}

// dist v12: overlap-maximizing config. R10 model: v10 (256^2) = 1 block/CU ->
// DMA, store, and VALU phases strictly SERIAL per CU (~30us); v11's 3-resident
// blocks failed to overlap -- suspected blocker: setprio(1) K-waves starving
// co-resident blocks' epilogue (store-issue + VALU at prio 0).
// Changes vs v11: (1) setprio REMOVED; (2) LDS halved to 32 KB (2 buffers x
// 16 KB) -> 5 blocks/CU resident; (3) 2-barrier/stage (required for 2-buffer
// safety: ISSUE(s+2) into buf s&1 only after compute(s) reads retire).
// 128x128 tile, 4 waves, 8 stages of BK=32, counted vmcnt(4) (exact: the
// K-loop has no other VMEM ops). Per buffer: 128 rows x 128 B, row r =
// [A(row0+r) 32fp16 || B(col0+r) 32fp16]; 16B quad l of row r at phys quad
// l ^ (r&7) (proven conflict-free). DMA: wave wv issues 4 instrs/stage
// (rg = wv*4+d covers LDS rows rg*8..+7; lane: g=lane>>3, p=lane&7, lq=p^g;
// lq<4 -> A quad lq, else B quad lq-4).
// Wave (wr,wc) = (wv>>1, wv&1) owns a 64x64 sub-tile -> acc[2][2].
// Epilogue: no LDS; anchor = column (valid by symmetry); ballot label packs;
// plain coalesced stores (v10-proven); 6 atomics from lanes 0..31.
__global__ __launch_bounds__(256, 5) void dist_kernel(const _Float16* __restrict__ Xf,
                                                      const int* __restrict__ tgt,
                                                      const float* __restrict__ sq,
                                                      float* __restrict__ dist,
                                                      float* ap, float* ang, float* anl) {
    __shared__ _Float16 lds[16384];         // 32 KiB: 2 stage-buffers x 8192 elems

    const int tid  = threadIdx.x;
    const int wv   = tid >> 6;              // 0..3
    const int lane = tid & 63;
    const int row0 = blockIdx.y * 128;
    const int col0 = blockIdx.x * 128;
    const int wr = wv >> 1, wc = wv & 1;

    // DMA per-lane constants
    const int g = lane >> 3, p = lane & 7, lq = p ^ g;
    const int sel  = (lq < 4 ? row0 : col0) + g;
    const int koff = (lq & 3) * 8;

    const int m0 = lane & 31;
    const int hi = lane >> 5;
    const int sw = m0 & 7;                   // frag swizzle key (all frag rows == m0 mod 8)

    floatx16 acc[2][2];
    #pragma unroll
    for (int mt = 0; mt < 2; ++mt)
        #pragma unroll
        for (int nt = 0; nt < 2; ++nt)
            #pragma unroll
            for (int r = 0; r < 16; ++r) acc[mt][nt][r] = 0.0f;

    // ---- stage DMA issue: 4 x gl_lds16 into buffer (st&1) ----
    #define ISSUE_STAGE(st)                                                       \
    do {                                                                          \
        _Float16* buf_ = lds + ((st) & 1) * 8192;                                 \
        const int k0_ = (st) * 32;                                                \
        _Pragma("unroll")                                                         \
        for (int d = 0; d < 4; ++d) {                                             \
            const int rg = wv * 4 + d;                                            \
            gl_lds16(Xf + (size_t)(sel + rg * 8) * D + k0_ + koff,                \
                     buf_ + rg * 512);                                            \
        }                                                                         \
    } while (0)

    ISSUE_STAGE(0);
    ISSUE_STAGE(1);

    #pragma unroll
    for (int s = 0; s < 8; ++s) {
        // wait for stage s's 4 loads; stage s+1's 4 stay in flight
        if (s < 7) { __asm__ volatile("s_waitcnt vmcnt(4)" ::: "memory"); }
        else       { __asm__ volatile("s_waitcnt vmcnt(0)" ::: "memory"); }
        __builtin_amdgcn_s_barrier();        // all waves' stage-s data in LDS

        const _Float16* buf = lds + (s & 1) * 8192;
        const _Float16* Ab  = buf + ((size_t)wr * 64 + m0) * 64;
        const _Float16* Bb  = buf + ((size_t)wc * 64 + m0) * 64;

        #pragma unroll
        for (int ks = 0; ks < 2; ++ks) {
            const int la  = ks * 2 + hi;             // 0..3
            const int poa = ((la       ^ sw) << 3);
            const int pob = (((la + 4) ^ sw) << 3);
            f16x8 a0 = *(const f16x8*)(Ab + poa);
            f16x8 a1 = *(const f16x8*)(Ab + 2048 + poa);   // +32 rows
            f16x8 b0 = *(const f16x8*)(Bb + pob);
            f16x8 b1 = *(const f16x8*)(Bb + 2048 + pob);
            acc[0][0] = __builtin_amdgcn_mfma_f32_32x32x16_f16(a0, b0, acc[0][0], 0, 0, 0);
            acc[0][1] = __builtin_amdgcn_mfma_f32_32x32x16_f16(a0, b1, acc[0][1], 0, 0, 0);
            acc[1][0] = __builtin_amdgcn_mfma_f32_32x32x16_f16(a1, b0, acc[1][0], 0, 0, 0);
            acc[1][1] = __builtin_amdgcn_mfma_f32_32x32x16_f16(a1, b1, acc[1][1], 0, 0, 0);
        }

        if (s < 6) {
            // buffer (s&1) reads retired before ISSUE(s+2) overwrites it
            __asm__ volatile("s_waitcnt lgkmcnt(0)" ::: "memory");
            __builtin_amdgcn_s_barrier();
            ISSUE_STAGE(s + 2);
        }
        __asm__ volatile("" ::: "memory");   // pin stage ordering
    }
    #undef ISSUE_STAGE

    // ---- Epilogue: d = sqrt(sqi + sqj - 2*dot); plain coalesced stores;
    // in-register column reduction (anchor = column, valid by symmetry).
    // C layout: col = lane&31 (+32*nt), row = (r&3) + 8*(r>>2) + 4*hi + 32*mt.
    const int rowbase = row0 + wr * 64;
    const int colbase = col0 + wc * 64;
    const int tl = tgt[rowbase + lane];
    const float sq_r = sq[rowbase + lane];
    const unsigned long long pb_0 = __ballot(tl & 1);
    const unsigned long long pb_1 = __ballot(tl & 2);
    const int gc0 = colbase + m0, gc1 = colbase + 32 + m0;
    const int tc0 = tgt[gc0], tc1 = tgt[gc1];
    const float sqc0 = sq[gc0], sqc1 = sq[gc1];
    const int rl_base = 4 * hi;

    float mx0 = 0.0f, mg0 = BIG, ml0 = BIG;
    float mx1 = 0.0f, mg1 = BIG, ml1 = BIG;

    #pragma unroll
    for (int mt = 0; mt < 2; ++mt) {
        #pragma unroll
        for (int r = 0; r < 16; ++r) {
            const int row_l = mt * 32 + (r & 3) + 8 * (r >> 2) + rl_base;
            const int grow  = rowbase + row_l;
            const float sqi = __shfl(sq_r, row_l);
            const float d0 = sqrtf(fmaxf(sqi + sqc0 - 2.0f * acc[mt][0][r], 0.0f));
            const float d1 = sqrtf(fmaxf(sqi + sqc1 - 2.0f * acc[mt][1][r], 0.0f));
            dist[(size_t)grow * N + gc0] = d0;
            dist[(size_t)grow * N + gc1] = d1;
            const int tr = (int)((pb_0 >> row_l) & 1) | ((int)((pb_1 >> row_l) & 1) << 1);
            mx0 = fmaxf(mx0, (tr == tc0) ? d0 : 0.0f);
            mg0 = fminf(mg0, (tr >  tc0) ? d0 : BIG);
            ml0 = fminf(ml0, (tr <  tc0) ? d0 : BIG);
            mx1 = fmaxf(mx1, (tr == tc1) ? d1 : 0.0f);
            mg1 = fminf(mg1, (tr >  tc1) ? d1 : BIG);
            ml1 = fminf(ml1, (tr <  tc1) ? d1 : BIG);
        }
    }
    // combine the two hi-halves (each reduced 32 of the 64 rows)
    mx0 = fmaxf(mx0, __shfl_xor(mx0, 32));
    mg0 = fminf(mg0, __shfl_xor(mg0, 32));
    ml0 = fminf(ml0, __shfl_xor(ml0, 32));
    mx1 = fmaxf(mx1, __shfl_xor(mx1, 32));
    mg1 = fminf(mg1, __shfl_xor(mg1, 32));
    ml1 = fminf(ml1, __shfl_xor(ml1, 32));

    if (hi == 0) {
        atomicMaxFloatPos(&ap[gc0],  mx0);
        atomicMinFloatPos(&ang[gc0], mg0);
        atomicMinFloatPos(&anl[gc0], ml0);
        atomicMaxFloatPos(&ap[gc1],  mx1);
        atomicMinFloatPos(&ang[gc1], mg1);
        atomicMinFloatPos(&anl[gc1], ml1);
    }
}

// Parallel finish: 16 blocks x 256 threads. Each block recomputes the global
// label histogram from tgt (16 KB, L2-hot), then handles 256 rows; partial
// loss/cnt accumulated into out via atomicAdd (prep zeroed the accumulators).
__global__ __launch_bounds__(256) void finish_kernel(const float* __restrict__ ap,
                                                     const float* __restrict__ ang,
                                                     const float* __restrict__ anl,
                                                     const int* __restrict__ tgt,
                                                     float* __restrict__ out) {
    __shared__ unsigned hs01[4], hs23[4];
    __shared__ float fs[4];
    __shared__ int   cs[4];
    const int tid = threadIdx.x, lane = tid & 63, wv = tid >> 6;

    // global histogram (every block recomputes; 4096 labels, int4 loads)
    int c[4] = {0, 0, 0, 0};
    #pragma unroll
    for (int j = 0; j < 4; ++j) {
        const int4 t4 = *(const int4*)&tgt[(j * 256 + tid) * 4];
        c[t4.x & 3]++; c[t4.y & 3]++; c[t4.z & 3]++; c[t4.w & 3]++;
    }
    unsigned p01 = (unsigned)c[0] | ((unsigned)c[1] << 16);
    unsigned p23 = (unsigned)c[2] | ((unsigned)c[3] << 16);
    #pragma unroll
    for (int off = 32; off; off >>= 1) {
        p01 += __shfl_down(p01, off);
        p23 += __shfl_down(p23, off);
    }
    if (lane == 0) { hs01[wv] = p01; hs23[wv] = p23; }
    __syncthreads();
    const unsigned a = hs01[0] + hs01[1] + hs01[2] + hs01[3];
    const unsigned b = hs23[0] + hs23[1] + hs23[2] + hs23[3];
    const int h0 = a & 0xFFFF, h1 = a >> 16, h2 = b & 0xFFFF, h3 = b >> 16;

    // per-row term + cnt
    const int row = blockIdx.x * 256 + tid;
    const int t = tgt[row] & 3;
    float term = fmaxf(ap[row] - fabsf(ang[row] - anl[row]) + MARGIN, 0.0f);
    const int h = (t == 0) ? h0 : (t == 1) ? h1 : (t == 2) ? h2 : h3;
    int cc = (h == 1) ? 1 : 0;

    #pragma unroll
    for (int off = 32; off; off >>= 1) {
        term += __shfl_down(term, off);
        cc   += __shfl_down(cc, off);
    }
    if (lane == 0) { fs[wv] = term; cs[wv] = cc; }
    __syncthreads();
    if (tid == 0) {
        const float ls = fs[0] + fs[1] + fs[2] + fs[3];
        const int   csum = cs[0] + cs[1] + cs[2] + cs[3];
        atomicAdd(&out[0], ls * (1.0f / N));
        atomicAdd(&out[1 + (size_t)N * N], (float)csum);
    }
}

extern "C" void kernel_launch(void* const* d_in, const int* in_sizes, int n_in,
                              void* d_out, int out_size, void* d_ws, size_t ws_size,
                              hipStream_t stream) {
    const float* x   = (const float*)d_in[0];
    const int*   tgt = (const int*)d_in[1];
    float* out = (float*)d_out;
    char*  ws  = (char*)d_ws;

    _Float16* Xf  = (_Float16*)ws;                    // 2 MiB, 16B-aligned
    float*    sq  = (float*)(ws + 2097152);
    float*    ap  = sq + 4096;
    float*    ang = sq + 8192;
    float*    anl = sq + 12288;

    prep_kernel<<<N / 4, 256, 0, stream>>>(x, sq, Xf, ap, ang, anl, out);
    dim3 grid(N / 128, N / 128);                      // 32 x 32 = 1024 blocks
    dist_kernel<<<grid, 256, 0, stream>>>(Xf, tgt, sq, out + 1, ap, ang, anl);
    finish_kernel<<<16, 256, 0, stream>>>(ap, ang, anl, tgt, out);
}

// Round 12
// 102.911 us; speedup vs baseline: 1.0199x; 1.0199x over previous
//
#include <hip/hip_runtime.h>

#define N 4096
#define D 256
#define MARGIN 0.3f
#define BIG 10000.0f

typedef _Float16 f16x8 __attribute__((ext_vector_type(8)));
typedef _Float16 f16x4 __attribute__((ext_vector_type(4)));
typedef float floatx16 __attribute__((ext_vector_type(16)));

__device__ inline void atomicMaxFloatPos(float* a, float v) {
    atomicMax((int*)a, __float_as_int(v));   // valid: all values >= 0
}
__device__ inline void atomicMinFloatPos(float* a, float v) {
    atomicMin((int*)a, __float_as_int(v));
}

// async 16B global -> LDS (wave-uniform LDS base + lane*16)
__device__ inline void gl_lds16(const void* g, void* l) {
    __builtin_amdgcn_global_load_lds(
        (const __attribute__((address_space(1))) unsigned int*)g,
        (__attribute__((address_space(3))) unsigned int*)l, 16, 0, 0);
}

// Wave per row: convert x -> fp16 Xf (RNE, row-major), sq from the CONVERTED
// values (so the Gram diagonal cancels exactly), init ap/ang/anl; block 0
// zeroes the two scalar outputs (finish accumulates into them via atomicAdd).
__global__ __launch_bounds__(256) void prep_kernel(const float* __restrict__ x,
                                                   float* __restrict__ sq,
                                                   _Float16* __restrict__ Xf,
                                                   float* ap, float* ang, float* anl,
                                                   float* __restrict__ out) {
    const int wave = threadIdx.x >> 6, lane = threadIdx.x & 63;
    const int row = blockIdx.x * 4 + wave;
    const float4 v = *(const float4*)(x + (size_t)row * D + lane * 4);
    f16x4 h;
    h[0] = (_Float16)v.x; h[1] = (_Float16)v.y;
    h[2] = (_Float16)v.z; h[3] = (_Float16)v.w;
    *(f16x4*)(Xf + (size_t)row * D + lane * 4) = h;
    const float c0 = (float)h[0], c1 = (float)h[1], c2 = (float)h[2], c3 = (float)h[3];
    float s = c0 * c0 + c1 * c1 + c2 * c2 + c3 * c3;
    #pragma unroll
    for (int off = 32; off; off >>= 1) s += __shfl_down(s, off);
    if (lane == 0) sq[row] = s;
    if (threadIdx.x < 4) {
        const int i = blockIdx.x * 4 + threadIdx.x;
        ap[i] = 0.0f; ang[i] = BIG; anl[i] = BIG;
    }
    if (blockIdx.x == 0 && threadIdx.x == 0) {
        out[0] = 0.0f;                       // loss accumulator
        out[1 + (size_t)N * N] = 0.0f;       // cnt accumulator
    }
}

// dist v13 == v10 verbatim (best measured: headline 102.3 us). Reverted after
// v11/v12 refuted the cross-block-overlap hypothesis (both regressed).
// Structure: 256x256 tile, 8 waves, deep staging pipeline: 8 stages of BK=32
// in FOUR LDS buffers (128 KB), 3 stages in flight, one barrier/stage,
// counted vmcnt (exact: the K-loop has no other VMEM ops). PLAIN cached
// stores (nt stores proven rate-limited, R8->R9: -5.3 us).
// Per buffer (32 KB): 256 rows x 128 B, row r = [A(row0+r) 32-fp16 slice ||
// B(col0+r) 32-fp16 slice]; 16B quad l of row r at phys quad l ^ (r&7).
// Wave (wr,wc) = (wv>>2, wv&3) owns a 128x64 sub-tile -> acc[4][2].
// Epilogue: no LDS; anchor = column (valid by symmetry); ballot label packs;
// coalesced stores; 6 atomics from lanes 0..31.
__global__ __launch_bounds__(512, 1) void dist_kernel(const _Float16* __restrict__ Xf,
                                                      const int* __restrict__ tgt,
                                                      const float* __restrict__ sq,
                                                      float* __restrict__ dist,
                                                      float* ap, float* ang, float* anl) {
    __shared__ _Float16 lds[65536];         // 128 KiB: 4 stage-buffers x 16384 elems

    const int tid  = threadIdx.x;
    const int wv   = tid >> 6;              // 0..7
    const int lane = tid & 63;
    const int row0 = blockIdx.y * 256;
    const int col0 = blockIdx.x * 256;
    const int wr = wv >> 2, wc = wv & 3;

    // DMA per-lane constants
    const int g = lane >> 3, p = lane & 7, lq = p ^ g;
    const int sel  = (lq < 4 ? row0 : col0) + g;
    const int koff = (lq & 3) * 8;

    const int m0 = lane & 31;
    const int hi = lane >> 5;
    const int sw = m0 & 7;                   // frag swizzle key (all frag rows == m0 mod 8)

    floatx16 acc[4][2];
    #pragma unroll
    for (int mt = 0; mt < 4; ++mt)
        #pragma unroll
        for (int nt = 0; nt < 2; ++nt)
            #pragma unroll
            for (int r = 0; r < 16; ++r) acc[mt][nt][r] = 0.0f;

    // ---- stage DMA issue: 4 x gl_lds16 into buffer (st&3) ----
    #define ISSUE_STAGE(st)                                                       \
    do {                                                                          \
        _Float16* buf_ = lds + ((st) & 3) * 16384;                                \
        const int k0_ = (st) * 32;                                                \
        _Pragma("unroll")                                                         \
        for (int d = 0; d < 4; ++d) {                                             \
            const int rg = wv * 4 + d;                                            \
            gl_lds16(Xf + (size_t)(sel + rg * 8) * D + k0_ + koff,                \
                     buf_ + rg * 512);                                            \
        }                                                                         \
    } while (0)

    ISSUE_STAGE(0);
    ISSUE_STAGE(1);
    ISSUE_STAGE(2);

    #pragma unroll
    for (int s = 0; s < 8; ++s) {
        // wait for stage s's 4 loads; stages s+1,s+2 (8 loads) stay in flight
        if (s < 6)      { __asm__ volatile("s_waitcnt vmcnt(8)" ::: "memory"); }
        else if (s == 6){ __asm__ volatile("s_waitcnt vmcnt(4)" ::: "memory"); }
        else            { __asm__ volatile("s_waitcnt vmcnt(0)" ::: "memory"); }
        __builtin_amdgcn_s_barrier();        // all waves' stage-s data in LDS
        if (s < 5) ISSUE_STAGE(s + 3);       // refill buffer (s-1)&3 (readers done)

        const _Float16* buf = lds + (s & 3) * 16384;
        const _Float16* Ab  = buf + ((size_t)wr * 128 + m0) * 64;
        const _Float16* Bb  = buf + ((size_t)wc * 64  + m0) * 64;

        __builtin_amdgcn_s_setprio(1);
        #pragma unroll
        for (int ks = 0; ks < 2; ++ks) {
            const int la  = ks * 2 + hi;             // 0..3
            const int poa = ((la       ^ sw) << 3);
            const int pob = (((la + 4) ^ sw) << 3);
            f16x8 b0 = *(const f16x8*)(Bb + pob);
            f16x8 b1 = *(const f16x8*)(Bb + 2048 + pob);
            #pragma unroll
            for (int mt = 0; mt < 4; ++mt) {
                f16x8 a = *(const f16x8*)(Ab + mt * 2048 + poa);
                acc[mt][0] = __builtin_amdgcn_mfma_f32_32x32x16_f16(a, b0, acc[mt][0], 0, 0, 0);
                acc[mt][1] = __builtin_amdgcn_mfma_f32_32x32x16_f16(a, b1, acc[mt][1], 0, 0, 0);
            }
        }
        __builtin_amdgcn_s_setprio(0);
        __asm__ volatile("" ::: "memory");   // pin stage ordering
    }
    #undef ISSUE_STAGE

    // ---- Epilogue: d = sqrt(sqi + sqj - 2*dot); PLAIN coalesced stores;
    // in-register column reduction (anchor = column, valid by symmetry).
    // C layout: col = lane&31 (+32*nt), row = (r&3) + 8*(r>>2) + 4*hi + 32*mt.
    const int rowA    = row0 + wr * 128;
    const int colbase = col0 + wc * 64;
    const int tl0 = tgt[rowA + lane];
    const int tl1 = tgt[rowA + 64 + lane];
    const float sqr0 = sq[rowA + lane];
    const float sqr1 = sq[rowA + 64 + lane];
    const unsigned long long pa0 = __ballot(tl0 & 1), pa1 = __ballot(tl0 & 2);
    const unsigned long long pb0 = __ballot(tl1 & 1), pb1 = __ballot(tl1 & 2);
    const int gc0 = colbase + m0, gc1 = colbase + 32 + m0;
    const int tc0 = tgt[gc0], tc1 = tgt[gc1];
    const float sqc0 = sq[gc0], sqc1 = sq[gc1];
    const int rl_base = 4 * hi;

    float mx0 = 0.0f, mg0 = BIG, ml0 = BIG;
    float mx1 = 0.0f, mg1 = BIG, ml1 = BIG;

    #pragma unroll
    for (int mt = 0; mt < 4; ++mt) {
        #pragma unroll
        for (int r = 0; r < 16; ++r) {
            const int row_l = mt * 32 + (r & 3) + 8 * (r >> 2) + rl_base;  // 0..127
            const int rl = row_l & 63;
            const int grow = rowA + row_l;
            const float sqi = __shfl(mt < 2 ? sqr0 : sqr1, rl);
            const float d0 = sqrtf(fmaxf(sqi + sqc0 - 2.0f * acc[mt][0][r], 0.0f));
            const float d1 = sqrtf(fmaxf(sqi + sqc1 - 2.0f * acc[mt][1][r], 0.0f));
            dist[(size_t)grow * N + gc0] = d0;
            dist[(size_t)grow * N + gc1] = d1;
            const unsigned long long q0 = (mt < 2 ? pa0 : pb0);
            const unsigned long long q1 = (mt < 2 ? pa1 : pb1);
            const int tr = (int)((q0 >> rl) & 1) | ((int)((q1 >> rl) & 1) << 1);
            mx0 = fmaxf(mx0, (tr == tc0) ? d0 : 0.0f);
            mg0 = fminf(mg0, (tr >  tc0) ? d0 : BIG);
            ml0 = fminf(ml0, (tr <  tc0) ? d0 : BIG);
            mx1 = fmaxf(mx1, (tr == tc1) ? d1 : 0.0f);
            mg1 = fminf(mg1, (tr >  tc1) ? d1 : BIG);
            ml1 = fminf(ml1, (tr <  tc1) ? d1 : BIG);
        }
    }
    // combine the two hi-halves (each reduced 64 of the 128 rows)
    mx0 = fmaxf(mx0, __shfl_xor(mx0, 32));
    mg0 = fminf(mg0, __shfl_xor(mg0, 32));
    ml0 = fminf(ml0, __shfl_xor(ml0, 32));
    mx1 = fmaxf(mx1, __shfl_xor(mx1, 32));
    mg1 = fminf(mg1, __shfl_xor(mg1, 32));
    ml1 = fminf(ml1, __shfl_xor(ml1, 32));

    if (hi == 0) {
        atomicMaxFloatPos(&ap[gc0],  mx0);
        atomicMinFloatPos(&ang[gc0], mg0);
        atomicMinFloatPos(&anl[gc0], ml0);
        atomicMaxFloatPos(&ap[gc1],  mx1);
        atomicMinFloatPos(&ang[gc1], mg1);
        atomicMinFloatPos(&anl[gc1], ml1);
    }
}

// Parallel finish: 16 blocks x 256 threads. Each block recomputes the global
// label histogram from tgt (16 KB, L2-hot), then handles 256 rows; partial
// loss/cnt accumulated into out via atomicAdd (prep zeroed the accumulators).
__global__ __launch_bounds__(256) void finish_kernel(const float* __restrict__ ap,
                                                     const float* __restrict__ ang,
                                                     const float* __restrict__ anl,
                                                     const int* __restrict__ tgt,
                                                     float* __restrict__ out) {
    __shared__ unsigned hs01[4], hs23[4];
    __shared__ float fs[4];
    __shared__ int   cs[4];
    const int tid = threadIdx.x, lane = tid & 63, wv = tid >> 6;

    // global histogram (every block recomputes; 4096 labels, int4 loads)
    int c[4] = {0, 0, 0, 0};
    #pragma unroll
    for (int j = 0; j < 4; ++j) {
        const int4 t4 = *(const int4*)&tgt[(j * 256 + tid) * 4];
        c[t4.x & 3]++; c[t4.y & 3]++; c[t4.z & 3]++; c[t4.w & 3]++;
    }
    unsigned p01 = (unsigned)c[0] | ((unsigned)c[1] << 16);
    unsigned p23 = (unsigned)c[2] | ((unsigned)c[3] << 16);
    #pragma unroll
    for (int off = 32; off; off >>= 1) {
        p01 += __shfl_down(p01, off);
        p23 += __shfl_down(p23, off);
    }
    if (lane == 0) { hs01[wv] = p01; hs23[wv] = p23; }
    __syncthreads();
    const unsigned a = hs01[0] + hs01[1] + hs01[2] + hs01[3];
    const unsigned b = hs23[0] + hs23[1] + hs23[2] + hs23[3];
    const int h0 = a & 0xFFFF, h1 = a >> 16, h2 = b & 0xFFFF, h3 = b >> 16;

    // per-row term + cnt
    const int row = blockIdx.x * 256 + tid;
    const int t = tgt[row] & 3;
    float term = fmaxf(ap[row] - fabsf(ang[row] - anl[row]) + MARGIN, 0.0f);
    const int h = (t == 0) ? h0 : (t == 1) ? h1 : (t == 2) ? h2 : h3;
    int cc = (h == 1) ? 1 : 0;

    #pragma unroll
    for (int off = 32; off; off >>= 1) {
        term += __shfl_down(term, off);
        cc   += __shfl_down(cc, off);
    }
    if (lane == 0) { fs[wv] = term; cs[wv] = cc; }
    __syncthreads();
    if (tid == 0) {
        const float ls = fs[0] + fs[1] + fs[2] + fs[3];
        const int   csum = cs[0] + cs[1] + cs[2] + cs[3];
        atomicAdd(&out[0], ls * (1.0f / N));
        atomicAdd(&out[1 + (size_t)N * N], (float)csum);
    }
}

extern "C" void kernel_launch(void* const* d_in, const int* in_sizes, int n_in,
                              void* d_out, int out_size, void* d_ws, size_t ws_size,
                              hipStream_t stream) {
    const float* x   = (const float*)d_in[0];
    const int*   tgt = (const int*)d_in[1];
    float* out = (float*)d_out;
    char*  ws  = (char*)d_ws;

    _Float16* Xf  = (_Float16*)ws;                    // 2 MiB, 16B-aligned
    float*    sq  = (float*)(ws + 2097152);
    float*    ap  = sq + 4096;
    float*    ang = sq + 8192;
    float*    anl = sq + 12288;

    prep_kernel<<<N / 4, 256, 0, stream>>>(x, sq, Xf, ap, ang, anl, out);
    dim3 grid(N / 256, N / 256);                      // 16 x 16 = 256 blocks
    dist_kernel<<<grid, 512, 0, stream>>>(Xf, tgt, sq, out + 1, ap, ang, anl);
    finish_kernel<<<16, 256, 0, stream>>>(ap, ang, anl, tgt, out);
}